// Round 5
// baseline (256.640 us; speedup 1.0000x reference)
//
#include <hip/hip_runtime.h>
#include <math.h>

#define Bn 512
#define Sn 1024
#define Tn 48
#define NSEG 8
#define SEGLEN 128

typedef _Float16 h4 __attribute__((ext_vector_type(4)));
typedef float    f4 __attribute__((ext_vector_type(4)));

static constexpr float LOG2E = 1.4426950408889634f;
static constexpr float LN2f  = 0.6931471805599453f;

// Unconditional: __has_builtin for amdgcn builtins returns 0 in the host pass.
#define MFMA16(A, B, C) __builtin_amdgcn_mfma_f32_16x16x16f16((A), (B), (C), 0, 0, 0)

// Segment-parallel CRF forward. One block = one batch; wave s evolves the
// 48x48 operator matrix of steps [1+128s, min(1+128(s+1),1024)) from identity
// (exp domain, f16 state, per-column power-of-2 renorm, stale-by-2 cadence —
// machinery identical to the absmax-0 round-3 kernel, 3 col-tiles wide).
// Then wave 0 applies the 8 matrices to the start vector via log2-domain lse.
__global__ __launch_bounds__(512)
void crf_fwd_seg(const float* __restrict__ em,
                 const float* __restrict__ mask,
                 const float* __restrict__ trans,
                 const float* __restrict__ startt,
                 const float* __restrict__ endt,
                 float* __restrict__ den_out)
{
  const int b   = blockIdx.x;
  const int tid = threadIdx.x;
  const int wid = tid >> 6;     // segment id 0..7
  const int l   = tid & 63;
  const int c16 = l & 15;       // column within a 16-col tile
  const int g   = l >> 4;       // row/k group: rows 4g..4g+3

  __shared__ __align__(16) float Lm[NSEG][48][49];  // log2 segment matrices
  __shared__ __align__(16) float mlds[Sn];          // staged mask row
  __shared__ float lwbuf[64];

  const float* __restrict__ emb = em + (size_t)b * Sn * Tn;
  const float* __restrict__ mkb = mask + (size_t)b * Sn;

  // stage this batch's mask into LDS (uniform per-step broadcast reads later)
  if (tid < Sn / 4) *(f4*)&mlds[4 * tid] = *(const f4*)(mkb + 4 * tid);

  // ---- static A fragments + global trans max (log2 domain) ----
  h4 Afr[3][3];
  float mtg;
  {
    float tl[3][3][4];
    float mt = -1e30f;
    #pragma unroll
    for (int rt = 0; rt < 3; ++rt)
      #pragma unroll
      for (int kt = 0; kt < 3; ++kt) {
        const f4 t4 = *(const f4*)(trans + (16 * rt + c16) * Tn + 16 * kt + 4 * g);
        #pragma unroll
        for (int i = 0; i < 4; ++i) {
          const float v = t4[i] * LOG2E;
          tl[rt][kt][i] = v;
          mt = fmaxf(mt, v);
        }
      }
    #pragma unroll
    for (int off = 1; off < 64; off <<= 1) mt = fmaxf(mt, __shfl_xor(mt, off));
    mtg = mt;
    #pragma unroll
    for (int rt = 0; rt < 3; ++rt)
      #pragma unroll
      for (int kt = 0; kt < 3; ++kt) {
        h4 r;
        #pragma unroll
        for (int i = 0; i < 4; ++i)
          r[i] = (_Float16)__builtin_amdgcn_exp2f(tl[rt][kt][i] - mtg);
        Afr[rt][kt] = r;
      }
  }

  // ---- segment state: W = I (48x48, f16 tiles), per-column shift Mc ----
  h4 Bfr[3][3];
  float Mc[3] = {0.f, 0.f, 0.f};
  float cnt = 0.f;
  #pragma unroll
  for (int kt = 0; kt < 3; ++kt)
    #pragma unroll
    for (int ct = 0; ct < 3; ++ct) {
      h4 r;
      #pragma unroll
      for (int i = 0; i < 4; ++i)
        r[i] = (_Float16)(((16 * kt + 4 * g + i) == (16 * ct + c16)) ? 1.0f : 0.0f);
      Bfr[kt][ct] = r;
    }

  auto STEP = [&](const f4& e0, const f4& e1, const f4& e2, float mk,
                  float sc0, float sc1, float sc2,
                  float sh0, float sh1, float sh2) {
    f4 eh[3];
    #pragma unroll
    for (int i = 0; i < 4; ++i) {
      eh[0][i] = __builtin_amdgcn_exp2f(fmaf(e0[i], LOG2E, -6.0f));
      eh[1][i] = __builtin_amdgcn_exp2f(fmaf(e1[i], LOG2E, -6.0f));
      eh[2][i] = __builtin_amdgcn_exp2f(fmaf(e2[i], LOG2E, -6.0f));
    }
    f4 acc[3][3];
    #pragma unroll
    for (int rt = 0; rt < 3; ++rt)
      #pragma unroll
      for (int ct = 0; ct < 3; ++ct) acc[rt][ct] = f4{0.f, 0.f, 0.f, 0.f};
    #pragma unroll
    for (int kt = 0; kt < 3; ++kt)
      #pragma unroll
      for (int rt = 0; rt < 3; ++rt)
        #pragma unroll
        for (int ct = 0; ct < 3; ++ct)
          acc[rt][ct] = MFMA16(Afr[rt][kt], Bfr[kt][ct], acc[rt][ct]);
    const float scv[3] = {sc0, sc1, sc2};
    const float shv[3] = {sh0, sh1, sh2};
    const bool on = (mk > 0.0f);
    #pragma unroll
    for (int rt = 0; rt < 3; ++rt)
      #pragma unroll
      for (int ct = 0; ct < 3; ++ct) {
        h4 nb;
        #pragma unroll
        for (int i = 0; i < 4; ++i)
          nb[i] = (_Float16)(acc[rt][ct][i] * eh[rt][i] * scv[ct]);  // RTN
        Bfr[rt][ct] = on ? nb : Bfr[rt][ct];
      }
    #pragma unroll
    for (int ct = 0; ct < 3; ++ct) Mc[ct] = fmaf(mk, shv[ct], Mc[ct]);
    cnt += mk;
  };

  // Per-column power-of-2 excess from the f16 state (exponent-exact).
  auto MEASURE = [&](float (&sh)[3], float (&sc)[3]) {
    #pragma unroll
    for (int ct = 0; ct < 3; ++ct) {
      float m = (float)Bfr[0][ct][0];
      #pragma unroll
      for (int rt = 0; rt < 3; ++rt)
        #pragma unroll
        for (int i = 0; i < 4; ++i) m = fmaxf(m, (float)Bfr[rt][ct][i]);
      m = fmaxf(m, __shfl_xor(m, 16));
      m = fmaxf(m, __shfl_xor(m, 32));
      int eb = ((__float_as_int(m) >> 23) & 0xff) - 127;
      eb = eb < -24 ? -24 : (eb > 40 ? 40 : eb);
      sh[ct] = (float)eb;
      sc[ct] = __int_as_float((127 - eb) << 23);   // exact 2^-eb
    }
  };

  auto loadE = [&](int s, f4& x, f4& y, f4& z) {
    const float* p = emb + (size_t)s * Tn + 4 * g;
    x = *(const f4*)(p);
    y = *(const f4*)(p + 16);
    z = *(const f4*)(p + 32);
  };

  __syncthreads();   // mask staged

  const int s_begin = 1 + SEGLEN * wid;
  const int nchunk  = (wid == 7) ? 31 : 32;
  float shP[3] = {0.f, 0.f, 0.f}, scP[3] = {1.f, 1.f, 1.f};
  float shA[3] = {0.f, 0.f, 0.f}, scA[3] = {1.f, 1.f, 1.f};

  f4 E0, E1, E2, N0, N1, N2;
  loadE(s_begin, E0, E1, E2);
  int s = s_begin;
  #pragma unroll 1
  for (int c = 0; c < nchunk; ++c) {
    loadE(s + 1, N0, N1, N2);
    STEP(E0, E1, E2, mlds[s], 1.f, 1.f, 1.f, 0.f, 0.f, 0.f);
    loadE(s + 2, E0, E1, E2);
    STEP(N0, N1, N2, mlds[s + 1], scP[0], scP[1], scP[2], shP[0], shP[1], shP[2]);
    MEASURE(shA, scA);
    loadE(s + 3, N0, N1, N2);
    STEP(E0, E1, E2, mlds[s + 2], 1.f, 1.f, 1.f, 0.f, 0.f, 0.f);
    loadE(s + 4, E0, E1, E2);   // max index s_begin+128 <= 1021: in bounds
    STEP(N0, N1, N2, mlds[s + 3], scA[0], scA[1], scA[2], shA[0], shA[1], shA[2]);
    MEASURE(shP, scP);
    s += 4;
  }
  if (wid == 7) {   // tail steps 1021..1023 (E holds 1021)
    loadE(1022, N0, N1, N2);
    STEP(E0, E1, E2, mlds[1021], 1.f, 1.f, 1.f, 0.f, 0.f, 0.f);
    loadE(1023, E0, E1, E2);
    STEP(N0, N1, N2, mlds[1022], scP[0], scP[1], scP[2], shP[0], shP[1], shP[2]);
    MEASURE(shA, scA);
    STEP(E0, E1, E2, mlds[1023], 1.f, 1.f, 1.f, 0.f, 0.f, 0.f);
  }

  // write log2 segment matrix: true log2 = log2(Wf16) + Mc[col] + (mtg+6)*cnt
  const float addc = (mtg + 6.0f) * cnt;
  #pragma unroll
  for (int kt = 0; kt < 3; ++kt)
    #pragma unroll
    for (int ct = 0; ct < 3; ++ct)
      #pragma unroll
      for (int i = 0; i < 4; ++i)
        Lm[wid][16 * kt + 4 * g + i][16 * ct + c16] =
            __builtin_amdgcn_logf((float)Bfr[kt][ct][i]) + Mc[ct] + addc;
  __syncthreads();

  // ---- combine: lw' = lse_c(L[j][c] + lw[c]), 8 segments, then end reduce ----
  if (wid == 0) {
    float lw = -INFINITY;
    if (l < Tn) lw = (startt[l] + emb[l]) * LOG2E;
    #pragma unroll 1
    for (int sg = 0; sg < NSEG; ++sg) {
      lwbuf[l] = lw;
      float nlw = lw;
      if (l < Tn) {
        float mj = -INFINITY;
        for (int cc = 0; cc < Tn; ++cc)
          mj = fmaxf(mj, Lm[sg][l][cc] + lwbuf[cc]);
        float ssum = 0.f;
        for (int cc = 0; cc < Tn; ++cc)
          ssum += __builtin_amdgcn_exp2f(Lm[sg][l][cc] + lwbuf[cc] - mj);
        nlw = mj + __builtin_amdgcn_logf(ssum);
      }
      lw = nlw;
    }
    float v = (l < Tn) ? lw + endt[l] * LOG2E : -INFINITY;
    float mv = v;
    #pragma unroll
    for (int off = 32; off; off >>= 1) mv = fmaxf(mv, __shfl_xor(mv, off));
    float zz = (l < Tn) ? __builtin_amdgcn_exp2f(v - mv) : 0.f;
    #pragma unroll
    for (int off = 32; off; off >>= 1) zz += __shfl_xor(zz, off);
    if (l == 0) den_out[b] = (mv + __builtin_amdgcn_logf(zz)) * LN2f;
  }
}

// Numerator: no recurrence -> fully parallel gather+reduce. One block per batch.
__global__ __launch_bounds__(256) void crf_numer(
    const float* __restrict__ em, const int* __restrict__ tags,
    const float* __restrict__ mask, const float* __restrict__ trans,
    const float* __restrict__ startt, const float* __restrict__ endt,
    float* __restrict__ num_out)
{
  const int b = blockIdx.x, t = threadIdx.x;
  const int*   tgb = tags + (size_t)b * Sn;
  const float* mkb = mask + (size_t)b * Sn;
  const float* emb = em + (size_t)b * Sn * Tn;

  const int s0 = t * 4;
  const int4 tg = *(const int4*)(tgb + s0);
  const f4   mk = *(const f4*)(mkb + s0);
  const int  tprev = (t == 0) ? 0 : tgb[s0 - 1];
  const int  tgarr[5] = {tprev, tg.x, tg.y, tg.z, tg.w};

  float acc  = 0.0f;
  float msum = mk[0] + mk[1] + mk[2] + mk[3];
  #pragma unroll
  for (int i = 0; i < 4; ++i) {
    const int s = s0 + i;
    if (s >= 1)
      acc += mk[i] * (emb[(size_t)s * Tn + tgarr[i + 1]] +
                      trans[tgarr[i + 1] * Tn + tgarr[i]]);
  }
  #pragma unroll
  for (int off = 32; off; off >>= 1) {
    acc  += __shfl_xor(acc, off);
    msum += __shfl_xor(msum, off);
  }
  __shared__ float ra[4], rm[4];
  if ((t & 63) == 0) { ra[t >> 6] = acc; rm[t >> 6] = msum; }
  __syncthreads();
  if (t == 0) {
    const float a = ra[0] + ra[1] + ra[2] + ra[3];
    const float m = rm[0] + rm[1] + rm[2] + rm[3];
    int last = (int)(m + 0.5f) - 1;
    if (last < 0) last = 0;
    const int lt = tgb[last];
    const int t0 = tgb[0];
    num_out[b] = startt[t0] + emb[t0] + a + endt[lt];
  }
}

__global__ __launch_bounds__(512) void reduce_loss(const float* __restrict__ den,
                                                   const float* __restrict__ num,
                                                   float* __restrict__ out) {
  __shared__ float red[8];
  const int t = threadIdx.x;
  float v = den[t] - num[t];
  #pragma unroll
  for (int off = 32; off; off >>= 1) v += __shfl_xor(v, off);
  if ((t & 63) == 0) red[t >> 6] = v;
  __syncthreads();
  if (t == 0) {
    float s = 0.f;
    #pragma unroll
    for (int wv = 0; wv < 8; ++wv) s += red[wv];
    out[0] = s * (1.0f / 512.0f);
  }
}

extern "C" void kernel_launch(void* const* d_in, const int* in_sizes, int n_in,
                              void* d_out, int out_size, void* d_ws, size_t ws_size,
                              hipStream_t stream) {
  const float* emissions = (const float*)d_in[0];
  const int*   tags      = (const int*)d_in[1];
  const float* mask      = (const float*)d_in[2];
  const float* trans     = (const float*)d_in[3];
  const float* startt    = (const float*)d_in[4];
  const float* endt      = (const float*)d_in[5];
  float* den_ws = (float*)d_ws;         // 512 floats
  float* num_ws = den_ws + Bn;          // 512 floats

  crf_numer<<<Bn, 256, 0, stream>>>(emissions, tags, mask, trans, startt, endt, num_ws);
  crf_fwd_seg<<<Bn, 512, 0, stream>>>(emissions, mask, trans, startt, endt, den_ws);
  reduce_loss<<<1, 512, 0, stream>>>(den_ws, num_ws, (float*)d_out);
}

// Round 6
// 208.432 us; speedup vs baseline: 1.2313x; 1.2313x over previous
//
#include <hip/hip_runtime.h>
#include <math.h>

#define Bn 512
#define Sn 1024
#define Tn 48
#define NSEG 8
#define SEGLEN 128

typedef _Float16 h2 __attribute__((ext_vector_type(2)));
typedef _Float16 h4 __attribute__((ext_vector_type(4)));
typedef float    f4 __attribute__((ext_vector_type(4)));

static constexpr float LOG2E = 1.4426950408889634f;
static constexpr float LN2f  = 0.6931471805599453f;

// Unconditional: __has_builtin for amdgcn builtins returns 0 in the host pass.
#define MFMA16(A, B, C) __builtin_amdgcn_mfma_f32_16x16x16f16((A), (B), (C), 0, 0, 0)

__device__ __forceinline__ h2 hmax2(h2 a, h2 b) {
#if __has_builtin(__builtin_elementwise_max)
  return __builtin_elementwise_max(a, b);
#else
  h2 r;
  r[0] = a[0] > b[0] ? a[0] : b[0];
  r[1] = a[1] > b[1] ? a[1] : b[1];
  return r;
#endif
}
__device__ __forceinline__ h2 cvt2(float a, float b) {
  return __builtin_bit_cast(h2, __builtin_amdgcn_cvt_pkrtz(a, b));
}
__device__ __forceinline__ h4 mkh4(h2 lo, h2 hi) {
  return __builtin_shufflevector(lo, hi, 0, 1, 2, 3);
}
__device__ __forceinline__ h2 loh(h4 v) { return __builtin_shufflevector(v, v, 0, 1); }
__device__ __forceinline__ h2 hih(h4 v) { return __builtin_shufflevector(v, v, 2, 3); }

// Memory-bound pregen: ehat[b][s][k] = f16(2^(em*log2e - 6)) (RTN converts).
__global__ __launch_bounds__(256) void ehgen(const float* __restrict__ em,
                                             _Float16* __restrict__ out) {
  const size_t total = (size_t)Bn * Sn * Tn;
  const size_t i = ((size_t)blockIdx.x * 256 + threadIdx.x) * 8;
  if (i >= total) return;
  const f4 a = *(const f4*)(em + i);
  const f4 b = *(const f4*)(em + i + 4);
  h4 o1, o2;
  #pragma unroll
  for (int j = 0; j < 4; ++j) {
    o1[j] = (_Float16)__builtin_amdgcn_exp2f(fmaf(a[j], LOG2E, -6.0f));
    o2[j] = (_Float16)__builtin_amdgcn_exp2f(fmaf(b[j], LOG2E, -6.0f));
  }
  *(h4*)(out + i) = o1;
  *(h4*)(out + i + 4) = o2;
}

// Segment-parallel CRF forward (geometry identical to the round-5 absmax-0
// kernel) with the VALU-slimmed step: packed-f16 eh multiply, sc-mul only on
// apply steps, wave-uniform scalar mask branch, packed-f16 MEASURE.
template <bool PRE>
__global__ __launch_bounds__(512, 4)
void crf_fwd_seg(const float* __restrict__ em,
                 const float* __restrict__ mask,
                 const float* __restrict__ trans,
                 const float* __restrict__ startt,
                 const float* __restrict__ endt,
                 const _Float16* __restrict__ eh16,
                 float* __restrict__ den_out)
{
  const int b   = blockIdx.x;
  const int tid = threadIdx.x;
  const int wid = tid >> 6;     // segment id 0..7
  const int l   = tid & 63;
  const int c16 = l & 15;       // column within a 16-col tile
  const int g   = l >> 4;       // row/k group: rows 4g..4g+3

  __shared__ __align__(16) float Lm[NSEG][48][49];  // log2 segment matrices
  __shared__ float lwbuf[64];

  const float*    __restrict__ emb = em + (size_t)b * Sn * Tn;
  const float*    __restrict__ mkb = mask + (size_t)b * Sn;
  const _Float16* __restrict__ ehL = PRE ? (eh16 + (size_t)b * Sn * Tn + 4 * g) : nullptr;
  const float*    __restrict__ emL = emb + 4 * g;

  // ---- static A fragments + global trans max (log2 domain) ----
  h4 Afr[3][3];
  float mtg;
  {
    float tl[3][3][4];
    float mt = -1e30f;
    #pragma unroll
    for (int rt = 0; rt < 3; ++rt)
      #pragma unroll
      for (int kt = 0; kt < 3; ++kt) {
        const f4 t4 = *(const f4*)(trans + (16 * rt + c16) * Tn + 16 * kt + 4 * g);
        #pragma unroll
        for (int i = 0; i < 4; ++i) {
          const float v = t4[i] * LOG2E;
          tl[rt][kt][i] = v;
          mt = fmaxf(mt, v);
        }
      }
    #pragma unroll
    for (int off = 1; off < 64; off <<= 1) mt = fmaxf(mt, __shfl_xor(mt, off));
    mtg = mt;
    #pragma unroll
    for (int rt = 0; rt < 3; ++rt)
      #pragma unroll
      for (int kt = 0; kt < 3; ++kt) {
        h4 r;
        #pragma unroll
        for (int i = 0; i < 4; ++i)
          r[i] = (_Float16)__builtin_amdgcn_exp2f(tl[rt][kt][i] - mtg);
        Afr[rt][kt] = r;
      }
  }

  // ---- segment state: W = I (48x48, f16 tiles), per-column shift Mc ----
  h4 Bfr[3][3];
  float Mc[3] = {0.f, 0.f, 0.f};
  float cnt = 0.f;
  #pragma unroll
  for (int kt = 0; kt < 3; ++kt)
    #pragma unroll
    for (int ct = 0; ct < 3; ++ct) {
      h4 r;
      #pragma unroll
      for (int i = 0; i < 4; ++i)
        r[i] = (_Float16)(((16 * kt + 4 * g + i) == (16 * ct + c16)) ? 1.0f : 0.0f);
      Bfr[kt][ct] = r;
    }

  auto STEP = [&](const h4& e0, const h4& e1, const h4& e2, float mkval,
                  bool APPLY, const float (&scv)[3], const float (&shv)[3]) {
    if (__int_as_float(__builtin_amdgcn_readfirstlane(__float_as_int(mkval))) > 0.0f) {
      f4 acc[3][3];
      #pragma unroll
      for (int rt = 0; rt < 3; ++rt)
        #pragma unroll
        for (int ct = 0; ct < 3; ++ct) acc[rt][ct] = f4{0.f, 0.f, 0.f, 0.f};
      #pragma unroll
      for (int kt = 0; kt < 3; ++kt)
        #pragma unroll
        for (int rt = 0; rt < 3; ++rt)
          #pragma unroll
          for (int ct = 0; ct < 3; ++ct)
            acc[rt][ct] = MFMA16(Afr[rt][kt], Bfr[kt][ct], acc[rt][ct]);
      const h4 ehv[3] = {e0, e1, e2};
      #pragma unroll
      for (int rt = 0; rt < 3; ++rt) {
        const h2 elo = loh(ehv[rt]);
        const h2 ehi = hih(ehv[rt]);
        #pragma unroll
        for (int ct = 0; ct < 3; ++ct) {
          f4 a = acc[rt][ct];
          if (APPLY) {
            a[0] *= scv[ct]; a[1] *= scv[ct]; a[2] *= scv[ct]; a[3] *= scv[ct];
          }
          const h2 lo = cvt2(a[0], a[1]) * elo;
          const h2 hi = cvt2(a[2], a[3]) * ehi;
          Bfr[rt][ct] = mkh4(lo, hi);
        }
      }
      if (APPLY) { Mc[0] += shv[0]; Mc[1] += shv[1]; Mc[2] += shv[2]; }
      cnt += 1.0f;
    }
  };

  auto MEASURE = [&](float (&sh)[3], float (&sc)[3]) {
    #pragma unroll
    for (int ct = 0; ct < 3; ++ct) {
      h2 m = loh(Bfr[0][ct]);
      m = hmax2(m, hih(Bfr[0][ct]));
      m = hmax2(m, loh(Bfr[1][ct]));
      m = hmax2(m, hih(Bfr[1][ct]));
      m = hmax2(m, loh(Bfr[2][ct]));
      m = hmax2(m, hih(Bfr[2][ct]));
      m = hmax2(m, __builtin_bit_cast(h2, __shfl_xor(__builtin_bit_cast(int, m), 16)));
      m = hmax2(m, __builtin_bit_cast(h2, __shfl_xor(__builtin_bit_cast(int, m), 32)));
      const float mf = fmaxf((float)m[0], (float)m[1]);
      int eb = ((__float_as_int(mf) >> 23) & 0xff) - 127;
      eb = eb < -15 ? -15 : (eb > 15 ? 15 : eb);
      sh[ct] = (float)eb;
      sc[ct] = __int_as_float((127 - eb) << 23);   // exact 2^-eb
    }
  };

  auto loadEH = [&](int s, h4& x, h4& y, h4& z) {
    if constexpr (PRE) {
      const _Float16* p = ehL + (size_t)s * Tn;
      x = *(const h4*)(p);
      y = *(const h4*)(p + 16);
      z = *(const h4*)(p + 32);
    } else {
      const float* p = emL + (size_t)s * Tn;
      const f4 a = *(const f4*)(p);
      const f4 b2 = *(const f4*)(p + 16);
      const f4 c2 = *(const f4*)(p + 32);
      f4 ea, eb2, ec;
      #pragma unroll
      for (int i = 0; i < 4; ++i) {
        ea[i]  = __builtin_amdgcn_exp2f(fmaf(a[i],  LOG2E, -6.0f));
        eb2[i] = __builtin_amdgcn_exp2f(fmaf(b2[i], LOG2E, -6.0f));
        ec[i]  = __builtin_amdgcn_exp2f(fmaf(c2[i], LOG2E, -6.0f));
      }
      x = mkh4(cvt2(ea[0], ea[1]), cvt2(ea[2], ea[3]));
      y = mkh4(cvt2(eb2[0], eb2[1]), cvt2(eb2[2], eb2[3]));
      z = mkh4(cvt2(ec[0], ec[1]), cvt2(ec[2], ec[3]));
    }
  };

  const int s_begin = 1 + SEGLEN * wid;
  const int nchunk  = (wid == 7) ? 31 : 32;   // wid7: steps 897..1020, tail 1021..1023
  float shP[3] = {0.f, 0.f, 0.f}, scP[3] = {1.f, 1.f, 1.f};
  float shA[3] = {0.f, 0.f, 0.f}, scA[3] = {1.f, 1.f, 1.f};
  const float sh1[3] = {0.f, 0.f, 0.f};
  const float sc1[3] = {1.f, 1.f, 1.f};

  h4 E0, E1, E2, N0, N1, N2;
  f4 mkc = *(const f4*)(mkb + s_begin);
  f4 mkn;
  loadEH(s_begin, E0, E1, E2);
  int s = s_begin;
  #pragma unroll 1
  for (int c = 0; c < nchunk; ++c) {
    mkn = *(const f4*)(mkb + ((c + 1 < nchunk) ? (s + 4) : s));  // safe addr
    loadEH(s + 1, N0, N1, N2);
    STEP(E0, E1, E2, mkc[0], false, sc1, sh1);
    loadEH(s + 2, E0, E1, E2);
    STEP(N0, N1, N2, mkc[1], true, scP, shP);
    MEASURE(shA, scA);
    loadEH(s + 3, N0, N1, N2);
    STEP(E0, E1, E2, mkc[2], false, sc1, sh1);
    loadEH(s + 4, E0, E1, E2);   // max index s_begin+128 <= 1021: in bounds
    STEP(N0, N1, N2, mkc[3], true, scA, shA);
    MEASURE(shP, scP);
    mkc = mkn;
    s += 4;
  }
  if (wid == 7) {   // tail steps 1021..1023 (E holds 1021)
    loadEH(1022, N0, N1, N2);
    STEP(E0, E1, E2, mkb[1021], false, sc1, sh1);
    loadEH(1023, E0, E1, E2);
    STEP(N0, N1, N2, mkb[1022], true, scP, shP);
    MEASURE(shA, scA);
    STEP(E0, E1, E2, mkb[1023], false, sc1, sh1);
  }

  // write log2 segment matrix: true log2 = log2(Wf16) + Mc[col] + (mtg+6)*cnt
  const float addc = (mtg + 6.0f) * cnt;
  #pragma unroll
  for (int kt = 0; kt < 3; ++kt)
    #pragma unroll
    for (int ct = 0; ct < 3; ++ct)
      #pragma unroll
      for (int i = 0; i < 4; ++i)
        Lm[wid][16 * kt + 4 * g + i][16 * ct + c16] =
            __builtin_amdgcn_logf((float)Bfr[kt][ct][i]) + Mc[ct] + addc;
  __syncthreads();

  // ---- combine: lw' = lse_c(L[j][c] + lw[c]), 8 segments, then end reduce ----
  if (wid == 0) {
    float lw = -INFINITY;
    if (l < Tn) lw = (startt[l] + emb[l]) * LOG2E;
    #pragma unroll 1
    for (int sg = 0; sg < NSEG; ++sg) {
      lwbuf[l] = lw;
      float nlw = lw;
      if (l < Tn) {
        float mj = -INFINITY;
        for (int cc = 0; cc < Tn; ++cc)
          mj = fmaxf(mj, Lm[sg][l][cc] + lwbuf[cc]);
        float ssum = 0.f;
        for (int cc = 0; cc < Tn; ++cc)
          ssum += __builtin_amdgcn_exp2f(Lm[sg][l][cc] + lwbuf[cc] - mj);
        nlw = mj + __builtin_amdgcn_logf(ssum);
      }
      lw = nlw;
    }
    float v = (l < Tn) ? lw + endt[l] * LOG2E : -INFINITY;
    float mv = v;
    #pragma unroll
    for (int off = 32; off; off >>= 1) mv = fmaxf(mv, __shfl_xor(mv, off));
    float zz = (l < Tn) ? __builtin_amdgcn_exp2f(v - mv) : 0.f;
    #pragma unroll
    for (int off = 32; off; off >>= 1) zz += __shfl_xor(zz, off);
    if (l == 0) den_out[b] = (mv + __builtin_amdgcn_logf(zz)) * LN2f;
  }
}

// Numerator: no recurrence -> fully parallel gather+reduce. One block per batch.
__global__ __launch_bounds__(256) void crf_numer(
    const float* __restrict__ em, const int* __restrict__ tags,
    const float* __restrict__ mask, const float* __restrict__ trans,
    const float* __restrict__ startt, const float* __restrict__ endt,
    float* __restrict__ num_out)
{
  const int b = blockIdx.x, t = threadIdx.x;
  const int*   tgb = tags + (size_t)b * Sn;
  const float* mkb = mask + (size_t)b * Sn;
  const float* emb = em + (size_t)b * Sn * Tn;

  const int s0 = t * 4;
  const int4 tg = *(const int4*)(tgb + s0);
  const f4   mk = *(const f4*)(mkb + s0);
  const int  tprev = (t == 0) ? 0 : tgb[s0 - 1];
  const int  tgarr[5] = {tprev, tg.x, tg.y, tg.z, tg.w};

  float acc  = 0.0f;
  float msum = mk[0] + mk[1] + mk[2] + mk[3];
  #pragma unroll
  for (int i = 0; i < 4; ++i) {
    const int s = s0 + i;
    if (s >= 1)
      acc += mk[i] * (emb[(size_t)s * Tn + tgarr[i + 1]] +
                      trans[tgarr[i + 1] * Tn + tgarr[i]]);
  }
  #pragma unroll
  for (int off = 32; off; off >>= 1) {
    acc  += __shfl_xor(acc, off);
    msum += __shfl_xor(msum, off);
  }
  __shared__ float ra[4], rm[4];
  if ((t & 63) == 0) { ra[t >> 6] = acc; rm[t >> 6] = msum; }
  __syncthreads();
  if (t == 0) {
    const float a = ra[0] + ra[1] + ra[2] + ra[3];
    const float m = rm[0] + rm[1] + rm[2] + rm[3];
    int last = (int)(m + 0.5f) - 1;
    if (last < 0) last = 0;
    const int lt = tgb[last];
    const int t0 = tgb[0];
    num_out[b] = startt[t0] + emb[t0] + a + endt[lt];
  }
}

__global__ __launch_bounds__(512) void reduce_loss(const float* __restrict__ den,
                                                   const float* __restrict__ num,
                                                   float* __restrict__ out) {
  __shared__ float red[8];
  const int t = threadIdx.x;
  float v = den[t] - num[t];
  #pragma unroll
  for (int off = 32; off; off >>= 1) v += __shfl_xor(v, off);
  if ((t & 63) == 0) red[t >> 6] = v;
  __syncthreads();
  if (t == 0) {
    float s = 0.f;
    #pragma unroll
    for (int wv = 0; wv < 8; ++wv) s += red[wv];
    out[0] = s * (1.0f / 512.0f);
  }
}

extern "C" void kernel_launch(void* const* d_in, const int* in_sizes, int n_in,
                              void* d_out, int out_size, void* d_ws, size_t ws_size,
                              hipStream_t stream) {
  const float* emissions = (const float*)d_in[0];
  const int*   tags      = (const int*)d_in[1];
  const float* mask      = (const float*)d_in[2];
  const float* trans     = (const float*)d_in[3];
  const float* startt    = (const float*)d_in[4];
  const float* endt      = (const float*)d_in[5];
  float* den_ws = (float*)d_ws;         // 512 floats
  float* num_ws = den_ws + Bn;          // 512 floats
  const size_t ehoff   = 4096;
  const size_t ehbytes = (size_t)Bn * Sn * Tn * sizeof(_Float16);
  _Float16* eh16 = (_Float16*)((char*)d_ws + ehoff);
  const bool pre = (ws_size >= ehoff + ehbytes);

  crf_numer<<<Bn, 256, 0, stream>>>(emissions, tags, mask, trans, startt, endt, num_ws);
  if (pre) {
    const int total8 = Bn * Sn * Tn / 8;
    ehgen<<<(total8 + 255) / 256, 256, 0, stream>>>(emissions, eh16);
    crf_fwd_seg<true><<<Bn, 512, 0, stream>>>(emissions, mask, trans, startt, endt,
                                              eh16, den_ws);
  } else {
    crf_fwd_seg<false><<<Bn, 512, 0, stream>>>(emissions, mask, trans, startt, endt,
                                               nullptr, den_ws);
  }
  reduce_loss<<<1, 512, 0, stream>>>(den_ws, num_ws, (float*)d_out);
}